// Round 1
// baseline (2527.287 us; speedup 1.0000x reference)
//
#include <hip/hip_runtime.h>

#define NNODES 50000
#define HID 128
#define NREL 9
#define NLAYERS 3
#define NEDGES 600000
#define MAX_PER_REL 72000

#define TM 64
#define BK 16

// ---------------- edge bucketing ----------------

__global__ void hist_kernel(const int* __restrict__ etype, int* __restrict__ counters) {
    __shared__ int h[NREL];
    int tid = threadIdx.x;
    if (tid < NREL) h[tid] = 0;
    __syncthreads();
    int e = blockIdx.x * blockDim.x + tid;
    if (e < NEDGES) atomicAdd(&h[etype[e]], 1);
    __syncthreads();
    if (tid < NREL) atomicAdd(&counters[tid], h[tid]);
}

__global__ void prefix_kernel(int* __restrict__ counters) {
    if (threadIdx.x == 0 && blockIdx.x == 0) {
        int run = 0;
        for (int r = 0; r < NREL; r++) {
            counters[16 + r] = run;   // offsets
            counters[32 + r] = run;   // cursors
            run += counters[r];
        }
    }
}

__global__ void bucket_kernel(const int* __restrict__ dst, const int* __restrict__ src,
                              const int* __restrict__ etype,
                              int* __restrict__ bsrc, int* __restrict__ bdst,
                              int* __restrict__ counters) {
    __shared__ int cnt[NREL];
    __shared__ int base[NREL];
    int tid = threadIdx.x;
    if (tid < NREL) cnt[tid] = 0;
    __syncthreads();
    int e = blockIdx.x * blockDim.x + tid;
    int t = 0, rank = 0;
    bool valid = (e < NEDGES);
    if (valid) {
        t = etype[e];
        rank = atomicAdd(&cnt[t], 1);
    }
    __syncthreads();
    if (tid < NREL) base[tid] = atomicAdd(&counters[32 + tid], cnt[tid]);
    __syncthreads();
    if (valid) {
        int pos = base[t] + rank;
        bsrc[pos] = src[e];
        bdst[pos] = dst[e];
    }
}

// ---------------- GEMM: Xr = (relu?)(A) @ B + bias ----------------
// A: [NNODES,128] row-major, B: [128,128] row-major (in x out), C: [NNODES,128]

__global__ __launch_bounds__(256) void gemm_bias(const float* __restrict__ A,
                                                 const float* __restrict__ B,
                                                 const float* __restrict__ bias,
                                                 float* __restrict__ C,
                                                 int relu_in) {
    __shared__ float As[BK][TM + 4];   // transposed [k][m], +4 pad keeps 16B align, 2-way bank alias max
    __shared__ float Bs[BK][HID];

    int tid  = threadIdx.x;
    int row0 = blockIdx.x * TM;

    int tr = (tid >> 5) * 8;      // 0..56 step 8
    int tc = (tid & 31) * 4;      // 0..124 step 4

    int la_row = tid >> 2;        // 0..63
    int la_k4  = (tid & 3) * 4;   // 0,4,8,12
    int lb_k   = tid >> 4;        // 0..15
    int lb_c   = (tid & 15) * 8;  // 0..120 step 8

    float acc[8][4];
#pragma unroll
    for (int i = 0; i < 8; i++)
#pragma unroll
        for (int j = 0; j < 4; j++) acc[i][j] = 0.0f;

    for (int k0 = 0; k0 < HID; k0 += BK) {
        float4 av = make_float4(0.f, 0.f, 0.f, 0.f);
        int arow = row0 + la_row;
        if (arow < NNODES) av = *(const float4*)(A + (size_t)arow * HID + k0 + la_k4);
        if (relu_in) {
            av.x = fmaxf(av.x, 0.f); av.y = fmaxf(av.y, 0.f);
            av.z = fmaxf(av.z, 0.f); av.w = fmaxf(av.w, 0.f);
        }
        float4 bv0 = *(const float4*)(B + (size_t)(k0 + lb_k) * HID + lb_c);
        float4 bv1 = *(const float4*)(B + (size_t)(k0 + lb_k) * HID + lb_c + 4);

        __syncthreads();
        As[la_k4 + 0][la_row] = av.x;
        As[la_k4 + 1][la_row] = av.y;
        As[la_k4 + 2][la_row] = av.z;
        As[la_k4 + 3][la_row] = av.w;
        *(float4*)&Bs[lb_k][lb_c]     = bv0;
        *(float4*)&Bs[lb_k][lb_c + 4] = bv1;
        __syncthreads();

#pragma unroll
        for (int k = 0; k < BK; k++) {
            float4 a0 = *(const float4*)&As[k][tr];
            float4 a1 = *(const float4*)&As[k][tr + 4];
            float4 bq = *(const float4*)&Bs[k][tc];
            float a[8] = {a0.x, a0.y, a0.z, a0.w, a1.x, a1.y, a1.z, a1.w};
            float b[4] = {bq.x, bq.y, bq.z, bq.w};
#pragma unroll
            for (int i = 0; i < 8; i++)
#pragma unroll
                for (int j = 0; j < 4; j++) acc[i][j] += a[i] * b[j];
        }
    }

    float4 bb = *(const float4*)(bias + tc);
#pragma unroll
    for (int i = 0; i < 8; i++) {
        int row = row0 + tr + i;
        if (row < NNODES) {
            float4 o;
            o.x = acc[i][0] + bb.x;
            o.y = acc[i][1] + bb.y;
            o.z = acc[i][2] + bb.z;
            o.w = acc[i][3] + bb.w;
            *(float4*)(C + (size_t)row * HID + tc) = o;
        }
    }
}

// ---------------- scatter: Hout[dst] += Xr[src] (atomic) ----------------

__global__ __launch_bounds__(256) void scatter_kernel(const float* __restrict__ Xr,
                                                      const int* __restrict__ bsrc,
                                                      const int* __restrict__ bdst,
                                                      const int* __restrict__ counters,
                                                      int r,
                                                      float* __restrict__ Hout) {
    int gid  = blockIdx.x * blockDim.x + threadIdx.x;
    int e    = gid >> 6;
    int lane = gid & 63;
    int cnt  = counters[r];
    if (e >= cnt) return;
    int off = counters[16 + r];
    int s = bsrc[off + e];
    int d = bdst[off + e];
    float2 v = *(const float2*)(Xr + (size_t)s * HID + lane * 2);
    float* p = Hout + (size_t)d * HID + lane * 2;
    unsafeAtomicAdd(p,     v.x);
    unsafeAtomicAdd(p + 1, v.y);
}

// ---------------- driver ----------------

extern "C" void kernel_launch(void* const* d_in, const int* in_sizes, int n_in,
                              void* d_out, int out_size, void* d_ws, size_t ws_size,
                              hipStream_t stream) {
    const int*   edge_index = (const int*)d_in[0];   // [2, NEDGES]: row0=dest, row1=src
    const int*   etype      = (const int*)d_in[1];   // [NEDGES]
    const float* emb        = (const float*)d_in[2]; // [NNODES, 128]
    const float* W          = (const float*)d_in[3]; // [3, 9, 128, 128]
    const float* Bias       = (const float*)d_in[4]; // [3, 9, 128]
    float*       out        = (float*)d_out;         // [NNODES, 128]

    const int* dst  = edge_index;
    const int* srcA = edge_index + NEDGES;

    // ws layout
    float* Xr = (float*)d_ws;
    float* HA = Xr + (size_t)NNODES * HID;
    float* HB = HA + (size_t)NNODES * HID;
    int*   bsrc     = (int*)(HB + (size_t)NNODES * HID);
    int*   bdst     = bsrc + NEDGES;
    int*   counters = bdst + NEDGES;   // 64 ints: [0..8]=counts, [16..24]=offsets, [32..40]=cursors

    hipMemsetAsync(counters, 0, 64 * sizeof(int), stream);
    hist_kernel<<<(NEDGES + 255) / 256, 256, 0, stream>>>(etype, counters);
    prefix_kernel<<<1, 64, 0, stream>>>(counters);
    bucket_kernel<<<(NEDGES + 255) / 256, 256, 0, stream>>>(dst, srcA, etype, bsrc, bdst, counters);

    const float* Hin = emb;
    for (int l = 0; l < NLAYERS; l++) {
        float* Hout = (l == 0) ? HA : ((l == 1) ? HB : out);
        hipMemsetAsync(Hout, 0, (size_t)NNODES * HID * sizeof(float), stream);
        int relu_in = (l > 0) ? 1 : 0;
        for (int r = 0; r < NREL; r++) {
            const float* Blr = W    + ((size_t)l * NREL + r) * HID * HID;
            const float* blr = Bias + ((size_t)l * NREL + r) * HID;
            gemm_bias<<<(NNODES + TM - 1) / TM, 256, 0, stream>>>(Hin, Blr, blr, Xr, relu_in);
            scatter_kernel<<<(MAX_PER_REL * 64) / 256, 256, 0, stream>>>(Xr, bsrc, bdst, counters, r, Hout);
        }
        Hin = Hout;
    }
}

// Round 2
// 1422.960 us; speedup vs baseline: 1.7761x; 1.7761x over previous
//
#include <hip/hip_runtime.h>

#define NNODES 50000
#define HID 128
#define NREL 9
#define NLAYERS 3
#define NEDGES 600000

#define NBINS (NREL * NNODES)          // 450000
#define SCAN_CHUNK 1024
#define NBLK ((NBINS + SCAN_CHUNK - 1) / SCAN_CHUNK)   // 440

#define TM 64
#define BK 16

// ---------------- CSR build: counting sort by (rel, dest) ----------------

__global__ void hist2_kernel(const int* __restrict__ dst, const int* __restrict__ etype,
                             int* __restrict__ bins) {
    int e = blockIdx.x * blockDim.x + threadIdx.x;
    if (e < NEDGES) {
        int bin = etype[e] * NNODES + dst[e];
        atomicAdd(&bins[bin], 1);
    }
}

// per-1024-chunk sums
__global__ __launch_bounds__(256) void scan_pass1(const int* __restrict__ bins,
                                                  int* __restrict__ blocksum) {
    __shared__ int red[256];
    int b = blockIdx.x, t = threadIdx.x;
    int i0 = b * SCAN_CHUNK + t * 4;
    int s = 0;
#pragma unroll
    for (int k = 0; k < 4; k++)
        if (i0 + k < NBINS) s += bins[i0 + k];
    red[t] = s;
    __syncthreads();
    for (int off = 128; off > 0; off >>= 1) {
        if (t < off) red[t] += red[t + off];
        __syncthreads();
    }
    if (t == 0) blocksum[b] = red[0];
}

// single-block exclusive scan of the 440 chunk sums
__global__ __launch_bounds__(512) void scan_pass2(const int* __restrict__ blocksum,
                                                  int* __restrict__ blockoff,
                                                  int* __restrict__ rowptr) {
    __shared__ int s[512];
    int t = threadIdx.x;
    int v = (t < NBLK) ? blocksum[t] : 0;
    s[t] = v;
    __syncthreads();
    for (int off = 1; off < 512; off <<= 1) {
        int x = (t >= off) ? s[t - off] : 0;
        __syncthreads();
        s[t] += x;
        __syncthreads();
    }
    if (t < NBLK) blockoff[t] = s[t] - v;   // exclusive
    if (t == 0) rowptr[NBINS] = NEDGES;
}

// local exclusive scan + global offset -> rowptr & cursors
__global__ __launch_bounds__(256) void scan_pass3(const int* __restrict__ bins,
                                                  const int* __restrict__ blockoff,
                                                  int* __restrict__ rowptr,
                                                  int* __restrict__ cursor) {
    __shared__ int sc[256];
    int b = blockIdx.x, t = threadIdx.x;
    int i0 = b * SCAN_CHUNK + t * 4;
    int v[4], p[4];
    int s = 0;
#pragma unroll
    for (int k = 0; k < 4; k++) {
        v[k] = (i0 + k < NBINS) ? bins[i0 + k] : 0;
        p[k] = s;          // thread-local exclusive prefix
        s += v[k];
    }
    sc[t] = s;
    __syncthreads();
    int inc = s;
    for (int off = 1; off < 256; off <<= 1) {
        int x = (t >= off) ? sc[t - off] : 0;
        __syncthreads();
        sc[t] += x;
        __syncthreads();
    }
    inc = sc[t];                       // inclusive over thread sums
    int base = blockoff[b] + (inc - s);
#pragma unroll
    for (int k = 0; k < 4; k++) {
        if (i0 + k < NBINS) {
            rowptr[i0 + k] = base + p[k];
            cursor[i0 + k] = base + p[k];
        }
    }
}

__global__ void place_kernel(const int* __restrict__ dst, const int* __restrict__ src,
                             const int* __restrict__ etype,
                             int* __restrict__ cursor, int* __restrict__ bsrc) {
    int e = blockIdx.x * blockDim.x + threadIdx.x;
    if (e < NEDGES) {
        int bin = etype[e] * NNODES + dst[e];
        int pos = atomicAdd(&cursor[bin], 1);
        bsrc[pos] = src[e];
    }
}

// ---------------- GEMM: Xr = (relu?)(A) @ B + bias ----------------

__global__ __launch_bounds__(256) void gemm_bias(const float* __restrict__ A,
                                                 const float* __restrict__ B,
                                                 const float* __restrict__ bias,
                                                 float* __restrict__ C,
                                                 int relu_in) {
    __shared__ float As[BK][TM + 4];
    __shared__ float Bs[BK][HID];

    int tid  = threadIdx.x;
    int row0 = blockIdx.x * TM;

    int tr = (tid >> 5) * 8;
    int tc = (tid & 31) * 4;

    int la_row = tid >> 2;
    int la_k4  = (tid & 3) * 4;
    int lb_k   = tid >> 4;
    int lb_c   = (tid & 15) * 8;

    float acc[8][4];
#pragma unroll
    for (int i = 0; i < 8; i++)
#pragma unroll
        for (int j = 0; j < 4; j++) acc[i][j] = 0.0f;

    for (int k0 = 0; k0 < HID; k0 += BK) {
        float4 av = make_float4(0.f, 0.f, 0.f, 0.f);
        int arow = row0 + la_row;
        if (arow < NNODES) av = *(const float4*)(A + (size_t)arow * HID + k0 + la_k4);
        if (relu_in) {
            av.x = fmaxf(av.x, 0.f); av.y = fmaxf(av.y, 0.f);
            av.z = fmaxf(av.z, 0.f); av.w = fmaxf(av.w, 0.f);
        }
        float4 bv0 = *(const float4*)(B + (size_t)(k0 + lb_k) * HID + lb_c);
        float4 bv1 = *(const float4*)(B + (size_t)(k0 + lb_k) * HID + lb_c + 4);

        __syncthreads();
        As[la_k4 + 0][la_row] = av.x;
        As[la_k4 + 1][la_row] = av.y;
        As[la_k4 + 2][la_row] = av.z;
        As[la_k4 + 3][la_row] = av.w;
        *(float4*)&Bs[lb_k][lb_c]     = bv0;
        *(float4*)&Bs[lb_k][lb_c + 4] = bv1;
        __syncthreads();

#pragma unroll
        for (int k = 0; k < BK; k++) {
            float4 a0 = *(const float4*)&As[k][tr];
            float4 a1 = *(const float4*)&As[k][tr + 4];
            float4 bq = *(const float4*)&Bs[k][tc];
            float a[8] = {a0.x, a0.y, a0.z, a0.w, a1.x, a1.y, a1.z, a1.w};
            float b[4] = {bq.x, bq.y, bq.z, bq.w};
#pragma unroll
            for (int i = 0; i < 8; i++)
#pragma unroll
                for (int j = 0; j < 4; j++) acc[i][j] += a[i] * b[j];
        }
    }

    float4 bb = *(const float4*)(bias + tc);
#pragma unroll
    for (int i = 0; i < 8; i++) {
        int row = row0 + tr + i;
        if (row < NNODES) {
            float4 o;
            o.x = acc[i][0] + bb.x;
            o.y = acc[i][1] + bb.y;
            o.z = acc[i][2] + bb.z;
            o.w = acc[i][3] + bb.w;
            *(float4*)(C + (size_t)row * HID + tc) = o;
        }
    }
}

// ---------------- gather: Hout[d] += sum_{e in CSR row (r,d)} Xr[src[e]] ----------------
// one wave per dest node; no atomics (each dest owned by exactly one wave)

__global__ __launch_bounds__(256) void gather_kernel(const float* __restrict__ Xr,
                                                     const int* __restrict__ bsrc,
                                                     const int* __restrict__ rowptr,
                                                     int r,
                                                     float* __restrict__ Hout) {
    int gid  = blockIdx.x * blockDim.x + threadIdx.x;
    int d    = gid >> 6;
    int lane = gid & 63;
    if (d >= NNODES) return;
    int base = r * NNODES + d;
    int rs = rowptr[base];
    int re = rowptr[base + 1];
    if (rs == re) return;
    float2 acc = make_float2(0.f, 0.f);
    for (int j = rs; j < re; j++) {
        int s = bsrc[j];
        float2 v = *(const float2*)(Xr + (size_t)s * HID + lane * 2);
        acc.x += v.x;
        acc.y += v.y;
    }
    float* p = Hout + (size_t)d * HID + lane * 2;
    float2 h = *(float2*)p;
    h.x += acc.x;
    h.y += acc.y;
    *(float2*)p = h;
}

// ---------------- driver ----------------

extern "C" void kernel_launch(void* const* d_in, const int* in_sizes, int n_in,
                              void* d_out, int out_size, void* d_ws, size_t ws_size,
                              hipStream_t stream) {
    const int*   edge_index = (const int*)d_in[0];   // [2, NEDGES]: row0=dest, row1=src
    const int*   etype      = (const int*)d_in[1];
    const float* emb        = (const float*)d_in[2];
    const float* W          = (const float*)d_in[3];
    const float* Bias       = (const float*)d_in[4];
    float*       out        = (float*)d_out;

    const int* dst  = edge_index;
    const int* srcA = edge_index + NEDGES;

    // ws layout
    float* Xr = (float*)d_ws;
    float* HA = Xr + (size_t)NNODES * HID;
    float* HB = HA + (size_t)NNODES * HID;
    int*   bsrc     = (int*)(HB + (size_t)NNODES * HID);
    int*   bins     = bsrc + NEDGES;
    int*   cursor   = bins + NBINS;
    int*   rowptr   = cursor + NBINS;        // NBINS+1 entries
    int*   blocksum = rowptr + NBINS + 1;
    int*   blockoff = blocksum + NBLK;

    hipMemsetAsync(bins, 0, NBINS * sizeof(int), stream);
    hist2_kernel<<<(NEDGES + 255) / 256, 256, 0, stream>>>(dst, etype, bins);
    scan_pass1<<<NBLK, 256, 0, stream>>>(bins, blocksum);
    scan_pass2<<<1, 512, 0, stream>>>(blocksum, blockoff, rowptr);
    scan_pass3<<<NBLK, 256, 0, stream>>>(bins, blockoff, rowptr, cursor);
    place_kernel<<<(NEDGES + 255) / 256, 256, 0, stream>>>(dst, srcA, etype, cursor, bsrc);

    const float* Hin = emb;
    for (int l = 0; l < NLAYERS; l++) {
        float* Hout = (l == 0) ? HA : ((l == 1) ? HB : out);
        hipMemsetAsync(Hout, 0, (size_t)NNODES * HID * sizeof(float), stream);
        int relu_in = (l > 0) ? 1 : 0;
        for (int r = 0; r < NREL; r++) {
            const float* Blr = W    + ((size_t)l * NREL + r) * HID * HID;
            const float* blr = Bias + ((size_t)l * NREL + r) * HID;
            gemm_bias<<<(NNODES + TM - 1) / TM, 256, 0, stream>>>(Hin, Blr, blr, Xr, relu_in);
            gather_kernel<<<(NNODES * 64 + 255) / 256, 256, 0, stream>>>(Xr, bsrc, rowptr, r, Hout);
        }
        Hin = Hout;
    }
}

// Round 3
// 698.108 us; speedup vs baseline: 3.6202x; 2.0383x over previous
//
#include <hip/hip_runtime.h>

#define NNODES 50000
#define HID 128
#define NREL 9
#define NLAYERS 3
#define NEDGES 600000

#define NBINS (NREL * NNODES)          // 450000
#define SCAN_CHUNK 1024
#define NBLK ((NBINS + SCAN_CHUNK - 1) / SCAN_CHUNK)   // 440

#define GM 64                           // GEMM M-tile
#define APITCH 136                      // 128 + 8 bf16 pad

typedef __attribute__((ext_vector_type(8))) short short8;
typedef __attribute__((ext_vector_type(4))) float f32x4;

__device__ __forceinline__ short f2bf(float f) {
    union { float f; unsigned u; } c; c.f = f;
    unsigned r = c.u + 0x7fff + ((c.u >> 16) & 1);   // RNE
    return (short)(r >> 16);
}

// ---------------- CSR build: counting sort by (rel, dest) ----------------

__global__ void hist2_kernel(const int* __restrict__ dst, const int* __restrict__ etype,
                             int* __restrict__ bins) {
    int e = blockIdx.x * blockDim.x + threadIdx.x;
    if (e < NEDGES) {
        int bin = etype[e] * NNODES + dst[e];
        atomicAdd(&bins[bin], 1);
    }
}

__global__ __launch_bounds__(256) void scan_pass1(const int* __restrict__ bins,
                                                  int* __restrict__ blocksum) {
    __shared__ int red[256];
    int b = blockIdx.x, t = threadIdx.x;
    int i0 = b * SCAN_CHUNK + t * 4;
    int s = 0;
#pragma unroll
    for (int k = 0; k < 4; k++)
        if (i0 + k < NBINS) s += bins[i0 + k];
    red[t] = s;
    __syncthreads();
    for (int off = 128; off > 0; off >>= 1) {
        if (t < off) red[t] += red[t + off];
        __syncthreads();
    }
    if (t == 0) blocksum[b] = red[0];
}

__global__ __launch_bounds__(512) void scan_pass2(const int* __restrict__ blocksum,
                                                  int* __restrict__ blockoff,
                                                  int* __restrict__ rowptr) {
    __shared__ int s[512];
    int t = threadIdx.x;
    int v = (t < NBLK) ? blocksum[t] : 0;
    s[t] = v;
    __syncthreads();
    for (int off = 1; off < 512; off <<= 1) {
        int x = (t >= off) ? s[t - off] : 0;
        __syncthreads();
        s[t] += x;
        __syncthreads();
    }
    if (t < NBLK) blockoff[t] = s[t] - v;
    if (t == 0) rowptr[NBINS] = NEDGES;
}

__global__ __launch_bounds__(256) void scan_pass3(const int* __restrict__ bins,
                                                  const int* __restrict__ blockoff,
                                                  int* __restrict__ rowptr,
                                                  int* __restrict__ cursor) {
    __shared__ int sc[256];
    int b = blockIdx.x, t = threadIdx.x;
    int i0 = b * SCAN_CHUNK + t * 4;
    int v[4], p[4];
    int s = 0;
#pragma unroll
    for (int k = 0; k < 4; k++) {
        v[k] = (i0 + k < NBINS) ? bins[i0 + k] : 0;
        p[k] = s;
        s += v[k];
    }
    sc[t] = s;
    __syncthreads();
    for (int off = 1; off < 256; off <<= 1) {
        int x = (t >= off) ? sc[t - off] : 0;
        __syncthreads();
        sc[t] += x;
        __syncthreads();
    }
    int base = blockoff[b] + (sc[t] - s);
#pragma unroll
    for (int k = 0; k < 4; k++) {
        if (i0 + k < NBINS) {
            rowptr[i0 + k] = base + p[k];
            cursor[i0 + k] = base + p[k];
        }
    }
}

__global__ void place_kernel(const int* __restrict__ dst, const int* __restrict__ src,
                             const int* __restrict__ etype,
                             int* __restrict__ cursor, int* __restrict__ bsrc) {
    int e = blockIdx.x * blockDim.x + threadIdx.x;
    if (e < NEDGES) {
        int bin = etype[e] * NNODES + dst[e];
        int pos = atomicAdd(&cursor[bin], 1);
        bsrc[pos] = src[e];
    }
}

// ---------------- W transpose+convert: Wt[l,r][n][k] = bf16(W[l,r][k][n]) ----------------

__global__ __launch_bounds__(256) void convert_w(const float* __restrict__ W,
                                                 short* __restrict__ Wt) {
    int lr = blockIdx.x;
    const float* w = W + (size_t)lr * HID * HID;
    short* o = Wt + (size_t)lr * HID * HID;
    int tid = threadIdx.x;
#pragma unroll 4
    for (int i = 0; i < 64; i++) {
        int elem = i * 256 + tid;
        int k = elem >> 7, n = elem & 127;
        o[n * HID + k] = f2bf(w[elem]);
    }
}

// ---------------- GEMM: Xr[r] = bf16( (relu?)(A) @ W[r] + bias[r] ) ----------------
// grid = (ceil(N/64), 9). A fp32 [N,128]; Wt bf16 [9][n][k]; Xr bf16 [9][N][128].

__global__ __launch_bounds__(256) void gemm_rgcn(const float* __restrict__ A,
                                                 const short* __restrict__ Wt,
                                                 const float* __restrict__ Bias,
                                                 short* __restrict__ Xr,
                                                 int relu_in) {
    __shared__ short As[GM][APITCH];
    __shared__ short Bs[HID][APITCH];

    int tid = threadIdx.x;
    int row0 = blockIdx.x * GM;
    int r = blockIdx.y;

    // stage A (fp32 -> relu? -> bf16)
    {
        int row = tid >> 2;
        int c0 = (tid & 3) * 32;
        int grow = row0 + row;
        short tmp[32];
        if (grow < NNODES) {
            const float* ap = A + (size_t)grow * HID + c0;
#pragma unroll
            for (int j = 0; j < 32; j += 4) {
                float4 v = *(const float4*)(ap + j);
                if (relu_in) {
                    v.x = fmaxf(v.x, 0.f); v.y = fmaxf(v.y, 0.f);
                    v.z = fmaxf(v.z, 0.f); v.w = fmaxf(v.w, 0.f);
                }
                tmp[j]     = f2bf(v.x);
                tmp[j + 1] = f2bf(v.y);
                tmp[j + 2] = f2bf(v.z);
                tmp[j + 3] = f2bf(v.w);
            }
        } else {
#pragma unroll
            for (int j = 0; j < 32; j++) tmp[j] = 0;
        }
#pragma unroll
        for (int j = 0; j < 32; j += 8)
            *(short8*)&As[row][c0 + j] = *(const short8*)&tmp[j];
    }
    // stage B (already bf16, [n][k] layout)
    {
        const short* wr = Wt + (size_t)r * HID * HID;
#pragma unroll
        for (int i = 0; i < 8; i++) {
            int elem = i * 2048 + tid * 8;
            short8 v = *(const short8*)(wr + elem);
            int n = elem >> 7, k = elem & 127;
            *(short8*)&Bs[n][k] = v;
        }
    }
    __syncthreads();

    int wave = tid >> 6, lane = tid & 63;
    int m0 = wave * 16;
    int lm = lane & 15, lq = lane >> 4;

    short8 af[4];
#pragma unroll
    for (int ks = 0; ks < 4; ks++)
        af[ks] = *(const short8*)&As[m0 + lm][ks * 32 + lq * 8];

    f32x4 acc[8];
#pragma unroll
    for (int nt = 0; nt < 8; nt++) acc[nt] = (f32x4){0.f, 0.f, 0.f, 0.f};

#pragma unroll
    for (int nt = 0; nt < 8; nt++) {
#pragma unroll
        for (int ks = 0; ks < 4; ks++) {
            short8 bf = *(const short8*)&Bs[nt * 16 + lm][ks * 32 + lq * 8];
            acc[nt] = __builtin_amdgcn_mfma_f32_16x16x32_bf16(af[ks], bf, acc[nt], 0, 0, 0);
        }
    }

    // epilogue: + bias (fp32), -> bf16.  C/D layout: col=lane&15, row=lq*4+reg
    const float* brow = Bias + (size_t)r * HID;
    short* xrow = Xr + (size_t)r * NNODES * HID;
#pragma unroll
    for (int nt = 0; nt < 8; nt++) {
        int n = nt * 16 + lm;
        float bv = brow[n];
#pragma unroll
        for (int reg = 0; reg < 4; reg++) {
            int grow = row0 + m0 + lq * 4 + reg;
            if (grow < NNODES) {
                xrow[(size_t)grow * HID + n] = f2bf(acc[nt][reg] + bv);
            }
        }
    }
}

// ---------------- gather: Hout[d] = sum_r sum_{e in CSR(r,d)} Xr[r][src[e]] ----------------
// one wave per dest; all 9 relations; unconditional store (no memset needed)

__global__ __launch_bounds__(256) void gather_all(const short* __restrict__ Xr,
                                                  const int* __restrict__ bsrc,
                                                  const int* __restrict__ rowptr,
                                                  float* __restrict__ Hout) {
    int gid  = blockIdx.x * blockDim.x + threadIdx.x;
    int d    = gid >> 6;
    int lane = gid & 63;
    if (d >= NNODES) return;
    float a0 = 0.f, a1 = 0.f;
    for (int r = 0; r < NREL; r++) {
        int base = r * NNODES + d;
        int rs = rowptr[base];
        int re = rowptr[base + 1];
        const unsigned* xb = (const unsigned*)(Xr + (size_t)r * NNODES * HID);
        for (int j = rs; j < re; j++) {
            int s = bsrc[j];
            unsigned v = xb[(size_t)s * (HID / 2) + lane];
            a0 += __uint_as_float(v << 16);
            a1 += __uint_as_float(v & 0xffff0000u);
        }
    }
    *(float2*)(Hout + (size_t)d * HID + lane * 2) = make_float2(a0, a1);
}

// ---------------- driver ----------------

extern "C" void kernel_launch(void* const* d_in, const int* in_sizes, int n_in,
                              void* d_out, int out_size, void* d_ws, size_t ws_size,
                              hipStream_t stream) {
    const int*   edge_index = (const int*)d_in[0];   // [2, NEDGES]: row0=dest, row1=src
    const int*   etype      = (const int*)d_in[1];
    const float* emb        = (const float*)d_in[2];
    const float* W          = (const float*)d_in[3]; // [3,9,128,128]
    const float* Bias       = (const float*)d_in[4]; // [3,9,128]
    float*       out        = (float*)d_out;

    const int* dst  = edge_index;
    const int* srcA = edge_index + NEDGES;

    // ws layout
    float* HA = (float*)d_ws;                               // 50000*128 f32
    float* HB = HA + (size_t)NNODES * HID;                  // 50000*128 f32
    short* Xr = (short*)(HB + (size_t)NNODES * HID);        // 9*50000*128 bf16
    short* Wt = Xr + (size_t)NREL * NNODES * HID;           // 27*128*128 bf16
    int*   bsrc     = (int*)(Wt + (size_t)NLAYERS * NREL * HID * HID);
    int*   bins     = bsrc + NEDGES;
    int*   cursor   = bins + NBINS;
    int*   rowptr   = cursor + NBINS;                       // NBINS+1
    int*   blocksum = rowptr + NBINS + 1;
    int*   blockoff = blocksum + NBLK;

    hipMemsetAsync(bins, 0, NBINS * sizeof(int), stream);
    hist2_kernel<<<(NEDGES + 255) / 256, 256, 0, stream>>>(dst, etype, bins);
    scan_pass1<<<NBLK, 256, 0, stream>>>(bins, blocksum);
    scan_pass2<<<1, 512, 0, stream>>>(blocksum, blockoff, rowptr);
    scan_pass3<<<NBLK, 256, 0, stream>>>(bins, blockoff, rowptr, cursor);
    place_kernel<<<(NEDGES + 255) / 256, 256, 0, stream>>>(dst, srcA, etype, cursor, bsrc);
    convert_w<<<NLAYERS * NREL, 256, 0, stream>>>(W, Wt);

    const float* Hin = emb;
    for (int l = 0; l < NLAYERS; l++) {
        float* Hout = (l == 0) ? HA : ((l == 1) ? HB : out);
        const short* Wtl = Wt + (size_t)l * NREL * HID * HID;
        const float* Bl  = Bias + (size_t)l * NREL * HID;
        dim3 grid((NNODES + GM - 1) / GM, NREL);
        gemm_rgcn<<<grid, 256, 0, stream>>>(Hin, Wtl, Bl, Xr, (l > 0) ? 1 : 0);
        gather_all<<<(NNODES * 64) / 256, 256, 0, stream>>>(Xr, bsrc, rowptr, Hout);
        Hin = Hout;
    }
}

// Round 5
// 685.313 us; speedup vs baseline: 3.6878x; 1.0187x over previous
//
#include <hip/hip_runtime.h>

#define NNODES 50000
#define HID 128
#define NREL 9
#define NLAYERS 3
#define NEDGES 600000

#define NBINS (NREL * NNODES)          // 450000, binned [dest][rel]
#define SCAN_CHUNK 1024
#define NBLK ((NBINS + SCAN_CHUNK - 1) / SCAN_CHUNK)   // 440

#define GM 64                           // dest rows per block
#define APITCH 136                      // 128 + 8 bf16 pad (272 B rows: 16B-aligned, 2-way banks max)

typedef __attribute__((ext_vector_type(8))) short short8;
typedef __attribute__((ext_vector_type(4))) short short4b;
typedef __attribute__((ext_vector_type(4))) float f32x4;

__device__ __forceinline__ short f2bf(float f) {
    union { float f; unsigned u; } c; c.f = f;
    unsigned r = c.u + 0x7fff + ((c.u >> 16) & 1);   // RNE
    return (short)(r >> 16);
}

// ---------------- CSR build: counting sort by (dest, rel) ----------------

__global__ void hist2_kernel(const int* __restrict__ dst, const int* __restrict__ etype,
                             int* __restrict__ bins) {
    int e = blockIdx.x * blockDim.x + threadIdx.x;
    if (e < NEDGES) {
        int bin = dst[e] * NREL + etype[e];
        atomicAdd(&bins[bin], 1);
    }
}

__global__ __launch_bounds__(256) void scan_pass1(const int* __restrict__ bins,
                                                  int* __restrict__ blocksum) {
    __shared__ int red[256];
    int b = blockIdx.x, t = threadIdx.x;
    int i0 = b * SCAN_CHUNK + t * 4;
    int s = 0;
#pragma unroll
    for (int k = 0; k < 4; k++)
        if (i0 + k < NBINS) s += bins[i0 + k];
    red[t] = s;
    __syncthreads();
    for (int off = 128; off > 0; off >>= 1) {
        if (t < off) red[t] += red[t + off];
        __syncthreads();
    }
    if (t == 0) blocksum[b] = red[0];
}

__global__ __launch_bounds__(512) void scan_pass2(const int* __restrict__ blocksum,
                                                  int* __restrict__ blockoff,
                                                  int* __restrict__ rowptr) {
    __shared__ int s[512];
    int t = threadIdx.x;
    int v = (t < NBLK) ? blocksum[t] : 0;
    s[t] = v;
    __syncthreads();
    for (int off = 1; off < 512; off <<= 1) {
        int x = (t >= off) ? s[t - off] : 0;
        __syncthreads();
        s[t] += x;
        __syncthreads();
    }
    if (t < NBLK) blockoff[t] = s[t] - v;
    if (t == 0) rowptr[NBINS] = NEDGES;
}

__global__ __launch_bounds__(256) void scan_pass3(const int* __restrict__ bins,
                                                  const int* __restrict__ blockoff,
                                                  int* __restrict__ rowptr,
                                                  int* __restrict__ cursor) {
    __shared__ int sc[256];
    int b = blockIdx.x, t = threadIdx.x;
    int i0 = b * SCAN_CHUNK + t * 4;
    int v[4], p[4];
    int s = 0;
#pragma unroll
    for (int k = 0; k < 4; k++) {
        v[k] = (i0 + k < NBINS) ? bins[i0 + k] : 0;
        p[k] = s;
        s += v[k];
    }
    sc[t] = s;
    __syncthreads();
    for (int off = 1; off < 256; off <<= 1) {
        int x = (t >= off) ? sc[t - off] : 0;
        __syncthreads();
        sc[t] += x;
        __syncthreads();
    }
    int base = blockoff[b] + (sc[t] - s);
#pragma unroll
    for (int k = 0; k < 4; k++) {
        if (i0 + k < NBINS) {
            rowptr[i0 + k] = base + p[k];
            cursor[i0 + k] = base + p[k];
        }
    }
}

__global__ void place_kernel(const int* __restrict__ dst, const int* __restrict__ src,
                             const int* __restrict__ etype,
                             int* __restrict__ cursor, int* __restrict__ bsrc) {
    int e = blockIdx.x * blockDim.x + threadIdx.x;
    if (e < NEDGES) {
        int bin = dst[e] * NREL + etype[e];
        int pos = atomicAdd(&cursor[bin], 1);
        bsrc[pos] = src[e];
    }
}

// ---------------- W transpose+convert: Wt[l,r][n][k] = bf16(W[l,r][k][n]) ----------------

__global__ __launch_bounds__(256) void convert_w(const float* __restrict__ W,
                                                 short* __restrict__ Wt) {
    int lr = blockIdx.x;
    const float* w = W + (size_t)lr * HID * HID;
    short* o = Wt + (size_t)lr * HID * HID;
    int tid = threadIdx.x;
#pragma unroll 4
    for (int i = 0; i < 64; i++) {
        int elem = i * 256 + tid;
        int k = elem >> 7, n = elem & 127;
        o[n * HID + k] = f2bf(w[elem]);
    }
}

// ---------------- fused layer: Hout[d] = relu?( sum_r S_r[d] @ W_r + c_{r,d} b_r ) ----------------
// S_r[d] = sum_{e in CSR(d,r)} Hin[src_e], aggregated in registers, staged bf16 in LDS,
// MFMA-accumulated over r. Xr never materialized.

__global__ __launch_bounds__(256) void fused_layer(const float* __restrict__ Hin,
                                                   const short* __restrict__ Wt,   // [9][n][k] bf16
                                                   const float* __restrict__ Bias, // [9][128]
                                                   const int* __restrict__ bsrc,
                                                   const int* __restrict__ rowptr, // [d*9+r]
                                                   float* __restrict__ Hout,
                                                   int relu_out) {
    __shared__ short Ss[GM][APITCH];
    __shared__ short Ws[HID][APITCH];
    __shared__ int   cnt_s[NREL][GM];

    int tid  = threadIdx.x;
    int wave = tid >> 6, lane = tid & 63;
    int row0 = blockIdx.x * GM;
    int m0   = wave * 16;
    int lm = lane & 15, lq = lane >> 4;   // lm: col-in-frag / sub-lane, lq: quad

    f32x4 acc[8];
#pragma unroll
    for (int nt = 0; nt < 8; nt++) acc[nt] = (f32x4){0.f, 0.f, 0.f, 0.f};

    for (int r = 0; r < NREL; r++) {
        __syncthreads();   // previous iteration's LDS reads complete

        // ---- aggregate 16 dests for this wave, 4 concurrently (16 lanes each) ----
#pragma unroll
        for (int g = 0; g < 4; g++) {
            int i = g * 4 + lq;          // dest index within wave's 16
            int d = row0 + m0 + i;
            int rs = 0, re = 0;
            if (d < NNODES) {
                int b = d * NREL + r;
                rs = rowptr[b];
                re = rowptr[b + 1];
            }
            float a0 = 0.f, a1 = 0.f, a2 = 0.f, a3 = 0.f;
            float b0 = 0.f, b1 = 0.f, b2 = 0.f, b3 = 0.f;
            for (int j = rs; j < re; j++) {
                int s = bsrc[j];
                const float* hp = Hin + (size_t)s * HID + lm * 4;
                float4 v0 = *(const float4*)hp;          // cols lm*4 .. +3
                float4 v1 = *(const float4*)(hp + 64);   // cols 64+lm*4 .. +3
                a0 += v0.x; a1 += v0.y; a2 += v0.z; a3 += v0.w;
                b0 += v1.x; b1 += v1.y; b2 += v1.z; b3 += v1.w;
            }
            short4b p0 = {f2bf(a0), f2bf(a1), f2bf(a2), f2bf(a3)};
            short4b p1 = {f2bf(b0), f2bf(b1), f2bf(b2), f2bf(b3)};
            *(short4b*)&Ss[m0 + i][lm * 4]      = p0;
            *(short4b*)&Ss[m0 + i][64 + lm * 4] = p1;
            if (lm == 0) cnt_s[r][m0 + i] = re - rs;
        }

        // ---- stage W_r (bf16 [n][k]) into LDS ----
        const short* wr = Wt + (size_t)r * HID * HID;
#pragma unroll
        for (int i = 0; i < 8; i++) {
            int elem = i * 2048 + tid * 8;
            short8 v = *(const short8*)(wr + elem);
            int n = elem >> 7, k = elem & 127;
            *(short8*)&Ws[n][k] = v;
        }
        __syncthreads();

        // ---- MFMA: acc += S_tile @ W_r ----
        short8 af[4];
#pragma unroll
        for (int ks = 0; ks < 4; ks++)
            af[ks] = *(const short8*)&Ss[m0 + lm][ks * 32 + lq * 8];
#pragma unroll
        for (int nt = 0; nt < 8; nt++) {
#pragma unroll
            for (int ks = 0; ks < 4; ks++) {
                short8 bf = *(const short8*)&Ws[nt * 16 + lm][ks * 32 + lq * 8];
                acc[nt] = __builtin_amdgcn_mfma_f32_16x16x32_bf16(af[ks], bf, acc[nt], 0, 0, 0);
            }
        }
    }

    // ---- epilogue: + sum_r cnt*bias, relu?, store fp32 ----
    // C/D layout: col = lane&15, row = lq*4 + reg
#pragma unroll
    for (int nt = 0; nt < 8; nt++) {
        int n = nt * 16 + lm;
        float bv[NREL];
#pragma unroll
        for (int r = 0; r < NREL; r++) bv[r] = Bias[r * HID + n];
#pragma unroll
        for (int reg = 0; reg < 4; reg++) {
            int rl = m0 + lq * 4 + reg;
            int d = row0 + rl;
            if (d < NNODES) {
                float b = 0.f;
#pragma unroll
                for (int r = 0; r < NREL; r++) b += (float)cnt_s[r][rl] * bv[r];
                float o = acc[nt][reg] + b;
                if (relu_out) o = fmaxf(o, 0.f);
                Hout[(size_t)d * HID + n] = o;
            }
        }
    }
}

// ---------------- driver ----------------

extern "C" void kernel_launch(void* const* d_in, const int* in_sizes, int n_in,
                              void* d_out, int out_size, void* d_ws, size_t ws_size,
                              hipStream_t stream) {
    const int*   edge_index = (const int*)d_in[0];   // [2, NEDGES]: row0=dest, row1=src
    const int*   etype      = (const int*)d_in[1];
    const float* emb        = (const float*)d_in[2];
    const float* W          = (const float*)d_in[3]; // [3,9,128,128]
    const float* Bias       = (const float*)d_in[4]; // [3,9,128]
    float*       out        = (float*)d_out;

    const int* dst  = edge_index;
    const int* srcA = edge_index + NEDGES;

    // ws layout
    float* HA = (float*)d_ws;                               // 50000*128 f32
    float* HB = HA + (size_t)NNODES * HID;                  // 50000*128 f32
    short* Wt = (short*)(HB + (size_t)NNODES * HID);        // 27*128*128 bf16
    int*   bsrc     = (int*)(Wt + (size_t)NLAYERS * NREL * HID * HID);
    int*   bins     = bsrc + NEDGES;
    int*   cursor   = bins + NBINS;
    int*   rowptr   = cursor + NBINS;                       // NBINS+1
    int*   blocksum = rowptr + NBINS + 1;
    int*   blockoff = blocksum + NBLK;

    hipMemsetAsync(bins, 0, NBINS * sizeof(int), stream);
    hist2_kernel<<<(NEDGES + 255) / 256, 256, 0, stream>>>(dst, etype, bins);
    scan_pass1<<<NBLK, 256, 0, stream>>>(bins, blocksum);
    scan_pass2<<<1, 512, 0, stream>>>(blocksum, blockoff, rowptr);
    scan_pass3<<<NBLK, 256, 0, stream>>>(bins, blockoff, rowptr, cursor);
    place_kernel<<<(NEDGES + 255) / 256, 256, 0, stream>>>(dst, srcA, etype, cursor, bsrc);
    convert_w<<<NLAYERS * NREL, 256, 0, stream>>>(W, Wt);

    const float* Hin = emb;
    for (int l = 0; l < NLAYERS; l++) {
        float* Hout = (l == 0) ? HA : ((l == 1) ? HB : out);
        const short* Wtl = Wt + (size_t)l * NREL * HID * HID;
        const float* Bl  = Bias + (size_t)l * NREL * HID;
        fused_layer<<<(NNODES + GM - 1) / GM, 256, 0, stream>>>(
            Hin, Wtl, Bl, bsrc, rowptr, Hout, (l + 1 < NLAYERS) ? 1 : 0);
        Hin = Hout;
    }
}